// Round 18
// baseline (346.824 us; speedup 1.0000x reference)
//
#include <hip/hip_runtime.h>

#define NNODES 100000
#define NEDGES 1600000
#define ETOT   1700000   // NEDGES + NNODES self-loops (csr slots)
#define NGRAPH 64
#define NEG    0.2f
#define NB_SCAN 98       // ceil(NNODES / 1024)
#define NPART  8
#define DPP    12500     // dst-nodes per scatter partition
#define SCAT_BPP 128
#define SCAT_CHR 12500   // NEDGES / (NPART*SCAT_BPP/NPART) = real edges per chunk
#define DSL    98        // ceil(DPP / SCAT_BPP) self-loop slots per chunk
#define PCH    1024      // pool1 nodes per block
#define NHB    1563      // ceil(NEDGES / 1024) hist blocks
#define NGB    1563      // ceil(NNODES / 64) gemm1 blocks
#define CSTR   16        // cnt padding stride (1 counter per 64B line)

using f32x2 = __attribute__((ext_vector_type(2))) float;

__device__ __forceinline__ float f4get(const float4& v, int j) {
    return j == 0 ? v.x : j == 1 ? v.y : j == 2 ? v.z : v.w;
}

__device__ __forceinline__ unsigned short f2bf(float f) {   // RNE f32->bf16
    unsigned u = __float_as_uint(f);
    u = (u + 0x7fffu + ((u >> 16) & 1u)) >> 16;
    return (unsigned short)u;
}
__device__ __forceinline__ float bf_lo(unsigned u) { return __uint_as_float(u << 16); }
__device__ __forceinline__ float bf_hi(unsigned u) { return __uint_as_float(u & 0xffff0000u); }

// ---- init: cnt[d*16]=1 (self-loop pre-counted), partial=0 ----
__global__ __launch_bounds__(256) void k_init(int* __restrict__ cnt, float* __restrict__ partial) {
    int t = threadIdx.x, b = blockIdx.x;
#pragma unroll
    for (int j = 0; j < 4; ++j) {
        int idx = b * 1024 + t * 4 + j;
        if (idx < NNODES) cnt[(size_t)idx * CSTR] = 1;
    }
    int pi = b * 256 + t;
    if (pi < NGRAPH * 40) partial[pi] = 0.f;
}

// ============ FUSED: hist (odd blocks, real edges only) + GEMM1 (even) ============
__global__ __launch_bounds__(256, 4) void k_fused1(const int* __restrict__ ei,
        int* __restrict__ cnt, int* __restrict__ rank,
        const float* __restrict__ x, const float* __restrict__ W1,
        const float* __restrict__ a1s, const float* __restrict__ a1d,
        unsigned* __restrict__ h1q, float* __restrict__ as1, float* __restrict__ ad1) {
    __shared__ float sX[64 * 128];    // 32 KB (gemm role only)
    int bid = blockIdx.x;
    if (bid & 1) {
        // ---- hist role: 4 real edges/thread; ranks start at 1 (slot 0 = self-loop) ----
        int hb = bid >> 1;
        int base = hb * 1024 + threadIdx.x;
        int e0 = base, e1 = base + 256, e2 = base + 512, e3 = base + 768;
        bool v0 = e0 < NEDGES, v1 = e1 < NEDGES, v2 = e2 < NEDGES, v3 = e3 < NEDGES;
        int d0 = 0, d1 = 0, d2 = 0, d3 = 0;
        if (v0) d0 = ei[NEDGES + e0];
        if (v1) d1 = ei[NEDGES + e1];
        if (v2) d2 = ei[NEDGES + e2];
        if (v3) d3 = ei[NEDGES + e3];
        int r0 = 0, r1 = 0, r2 = 0, r3 = 0;
        if (v0) r0 = atomicAdd(&cnt[(size_t)d0 * CSTR], 1);
        if (v1) r1 = atomicAdd(&cnt[(size_t)d1 * CSTR], 1);
        if (v2) r2 = atomicAdd(&cnt[(size_t)d2 * CSTR], 1);
        if (v3) r3 = atomicAdd(&cnt[(size_t)d3 * CSTR], 1);
        if (v0) rank[e0] = r0;
        if (v1) rank[e1] = r1;
        if (v2) rank[e2] = r2;
        if (v3) rank[e3] = r3;
        return;
    }
    // ---- gemm1 role ----
    int gb = bid >> 1;
    if (gb >= NGB) return;
    int t = threadIdx.x;
    int nbase = gb * 64;
    int nrows = NNODES - nbase; if (nrows > 64) nrows = 64;
    {
        const float4* X4 = (const float4*)(x + (size_t)nbase * 128);
        float4* sX4 = (float4*)sX;
        for (int i = t; i < nrows * 32; i += 256) sX4[i] = X4[i];
    }
    __syncthreads();

    int colg = t & 31, rowg = t >> 5;
    int c0 = colg * 4, n0 = rowg * 8;
    float acc[8][4];
#pragma unroll
    for (int i = 0; i < 8; ++i)
        acc[i][0] = acc[i][1] = acc[i][2] = acc[i][3] = 0.f;

    for (int k = 0; k < 128; k += 4) {
        float4 w0 = *(const float4*)&W1[(size_t)(k + 0) * 128 + c0];
        float4 w1 = *(const float4*)&W1[(size_t)(k + 1) * 128 + c0];
        float4 w2 = *(const float4*)&W1[(size_t)(k + 2) * 128 + c0];
        float4 w3 = *(const float4*)&W1[(size_t)(k + 3) * 128 + c0];
#pragma unroll
        for (int i = 0; i < 8; ++i) {
            float4 xv = *(const float4*)&sX[(n0 + i) * 128 + k];
            acc[i][0] = fmaf(xv.x, w0.x, acc[i][0]); acc[i][1] = fmaf(xv.x, w0.y, acc[i][1]);
            acc[i][2] = fmaf(xv.x, w0.z, acc[i][2]); acc[i][3] = fmaf(xv.x, w0.w, acc[i][3]);
            acc[i][0] = fmaf(xv.y, w1.x, acc[i][0]); acc[i][1] = fmaf(xv.y, w1.y, acc[i][1]);
            acc[i][2] = fmaf(xv.y, w1.z, acc[i][2]); acc[i][3] = fmaf(xv.y, w1.w, acc[i][3]);
            acc[i][0] = fmaf(xv.z, w2.x, acc[i][0]); acc[i][1] = fmaf(xv.z, w2.y, acc[i][1]);
            acc[i][2] = fmaf(xv.z, w2.z, acc[i][2]); acc[i][3] = fmaf(xv.z, w2.w, acc[i][3]);
            acc[i][0] = fmaf(xv.w, w3.x, acc[i][0]); acc[i][1] = fmaf(xv.w, w3.y, acc[i][1]);
            acc[i][2] = fmaf(xv.w, w3.z, acc[i][2]); acc[i][3] = fmaf(xv.w, w3.w, acc[i][3]);
        }
    }

    int head = colg >> 3;
    float ws0 = a1s[c0], ws1 = a1s[c0 + 1], ws2 = a1s[c0 + 2], ws3 = a1s[c0 + 3];
    float wd0 = a1d[c0], wd1 = a1d[c0 + 1], wd2 = a1d[c0 + 2], wd3 = a1d[c0 + 3];
#pragma unroll
    for (int i = 0; i < 8; ++i) {
        int n = n0 + i;
        float ps = acc[i][0] * ws0 + acc[i][1] * ws1 + acc[i][2] * ws2 + acc[i][3] * ws3;
        float pd = acc[i][0] * wd0 + acc[i][1] * wd1 + acc[i][2] * wd2 + acc[i][3] * wd3;
        ps += __shfl_xor(ps, 1); ps += __shfl_xor(ps, 2); ps += __shfl_xor(ps, 4);
        pd += __shfl_xor(pd, 1); pd += __shfl_xor(pd, 2); pd += __shfl_xor(pd, 4);
        if (n < nrows) {
            int q = __builtin_amdgcn_cvt_pk_fp8_f32(acc[i][0], acc[i][1], 0, false);
            q = __builtin_amdgcn_cvt_pk_fp8_f32(acc[i][2], acc[i][3], q, true);
            h1q[((size_t)(nbase + n)) * 32 + colg] = (unsigned)q;
            if ((colg & 7) == 0) {
                as1[(size_t)(nbase + n) * 4 + head] = ps;
                ad1[(size_t)(nbase + n) * 4 + head] = pd;
            }
        }
    }
}

__global__ __launch_bounds__(256) void k_scan1(const int* __restrict__ cnt,
                                               int* __restrict__ excl,
                                               int* __restrict__ bsum) {
    __shared__ int tmp[256];
    int t = threadIdx.x;
    int base = blockIdx.x * 1024 + t * 4;
    int v0 = base + 0 < NNODES ? cnt[(size_t)(base + 0) * CSTR] : 0;
    int v1 = base + 1 < NNODES ? cnt[(size_t)(base + 1) * CSTR] : 0;
    int v2 = base + 2 < NNODES ? cnt[(size_t)(base + 2) * CSTR] : 0;
    int v3 = base + 3 < NNODES ? cnt[(size_t)(base + 3) * CSTR] : 0;
    int tot = v0 + v1 + v2 + v3;
    tmp[t] = tot;
    __syncthreads();
    for (int off = 1; off < 256; off <<= 1) {
        int x = (t >= off) ? tmp[t - off] : 0;
        __syncthreads();
        tmp[t] += x;
        __syncthreads();
    }
    int tbase = tmp[t] - tot;
    if (base + 0 < NNODES) excl[base + 0] = tbase;
    if (base + 1 < NNODES) excl[base + 1] = tbase + v0;
    if (base + 2 < NNODES) excl[base + 2] = tbase + v0 + v1;
    if (base + 3 < NNODES) excl[base + 3] = tbase + v0 + v1 + v2;
    if (t == 255) bsum[blockIdx.x] = tmp[255];
}

// offs[n] = global exclusive prefix
__global__ __launch_bounds__(256) void k_offs(const int* __restrict__ excl,
                                              const int* __restrict__ bsum,
                                              int* __restrict__ offs) {
    __shared__ int sp;
    int b = blockIdx.x, t = threadIdx.x;
    if (t == 0) {
        int p = 0;
        for (int i = 0; i < b; ++i) p += bsum[i];
        sp = p;
    }
    __syncthreads();
    int prefix = sp;
#pragma unroll
    for (int j = 0; j < 4; ++j) {
        int idx = b * 1024 + t * 4 + j;
        if (idx < NNODES) offs[idx] = excl[idx] + prefix;
    }
}

// dst-range partitioned scatter: real edges (ranks >=1) + self-loop slot-0 writes
__global__ __launch_bounds__(256) void k_scatter(const int* __restrict__ ei,
                                                 const int* __restrict__ rank,
                                                 const int* __restrict__ offs,
                                                 int* __restrict__ csr_src) {
    int p = blockIdx.x & (NPART - 1);
    int chunk = blockIdx.x / NPART;
    int dlo = p * DPP, dhi = dlo + DPP;
    // self-loop slot 0 for this chunk's share of dst range (near-sequential writes)
    {
        int d = dlo + chunk * DSL + threadIdx.x;
        if (threadIdx.x < DSL && d < dhi) csr_src[offs[d]] = d;
    }
    int e0 = chunk * SCAT_CHR;
    int e1 = e0 + SCAT_CHR; if (e1 > NEDGES) e1 = NEDGES;
    for (int e = e0 + threadIdx.x; e < e1; e += 1024) {
        int eA = e, eB = e + 256, eC = e + 512, eD = e + 768;
        bool vA = eA < e1, vB = eB < e1, vC = eC < e1, vD = eD < e1;
        int dA = -1, dB = -1, dC = -1, dD = -1;
        if (vA) dA = ei[NEDGES + eA];
        if (vB) dB = ei[NEDGES + eB];
        if (vC) dC = ei[NEDGES + eC];
        if (vD) dD = ei[NEDGES + eD];
        if (dA >= dlo && dA < dhi) csr_src[offs[dA] + rank[eA]] = ei[eA];
        if (dB >= dlo && dB < dhi) csr_src[offs[dB] + rank[eB]] = ei[eB];
        if (dC >= dlo && dC < dhi) csr_src[offs[dC] + rank[eC]] = ei[eC];
        if (dD >= dlo && dD < dhi) csr_src[offs[dD] + rank[eD]] = ei[eD];
    }
}

// -------- layer-1 aggregation: 32-lane groups, 4x-unrolled gather --------
__global__ __launch_bounds__(256) void k_node1(const int* __restrict__ csr_src,
        const int* __restrict__ offs, const int* __restrict__ cnt,
        const unsigned* __restrict__ h1q,
        const float4* __restrict__ as1v, const float4* __restrict__ ad1v,
        unsigned* __restrict__ out1b) {
    __shared__ float4 exbuf[8][32];
    int t = threadIdx.x;
    int grp = t >> 5, lane = t & 31;
    int node = blockIdx.x * 8 + grp;
    if (node >= NNODES) return;
    int head = lane >> 3;
    int off = offs[node];
    int deg = cnt[(size_t)node * CSTR];
    float4 adv = ad1v[node];
    float4 dp = make_float4(0.f, 0.f, 0.f, 0.f);
    float4 acc = make_float4(0.f, 0.f, 0.f, 0.f);
    const float* exs = (const float*)&exbuf[grp][0];

    for (int base = 0; base < deg; base += 32) {
        int m = deg - base; if (m > 32) m = 32;
        int sv = 0;
        if (lane < m) {
            sv = csr_src[off + base + lane];
            float4 av = as1v[sv];
            float v; float4 e;
            v = av.x + adv.x; v = v > 0.f ? v : NEG * v; e.x = __expf(v);
            v = av.y + adv.y; v = v > 0.f ? v : NEG * v; e.y = __expf(v);
            v = av.z + adv.z; v = v > 0.f ? v : NEG * v; e.z = __expf(v);
            v = av.w + adv.w; v = v > 0.f ? v : NEG * v; e.w = __expf(v);
            exbuf[grp][lane] = e;
            dp.x += e.x; dp.y += e.y; dp.z += e.z; dp.w += e.w;
        }
        __builtin_amdgcn_wave_barrier();
        int i = 0;
        for (; i + 4 <= m; i += 4) {
            int s0 = __shfl(sv, i + 0, 32);
            int s1 = __shfl(sv, i + 1, 32);
            int s2 = __shfl(sv, i + 2, 32);
            int s3 = __shfl(sv, i + 3, 32);
            unsigned q0 = h1q[(size_t)s0 * 32 + lane];
            unsigned q1 = h1q[(size_t)s1 * 32 + lane];
            unsigned q2 = h1q[(size_t)s2 * 32 + lane];
            unsigned q3 = h1q[(size_t)s3 * 32 + lane];
            float a0 = exs[(i + 0) * 4 + head];
            float a1 = exs[(i + 1) * 4 + head];
            float a2 = exs[(i + 2) * 4 + head];
            float a3 = exs[(i + 3) * 4 + head];
            f32x2 lo, hi;
            lo = __builtin_amdgcn_cvt_pk_f32_fp8((int)q0, false);
            hi = __builtin_amdgcn_cvt_pk_f32_fp8((int)q0, true);
            acc.x = fmaf(lo.x, a0, acc.x); acc.y = fmaf(lo.y, a0, acc.y);
            acc.z = fmaf(hi.x, a0, acc.z); acc.w = fmaf(hi.y, a0, acc.w);
            lo = __builtin_amdgcn_cvt_pk_f32_fp8((int)q1, false);
            hi = __builtin_amdgcn_cvt_pk_f32_fp8((int)q1, true);
            acc.x = fmaf(lo.x, a1, acc.x); acc.y = fmaf(lo.y, a1, acc.y);
            acc.z = fmaf(hi.x, a1, acc.z); acc.w = fmaf(hi.y, a1, acc.w);
            lo = __builtin_amdgcn_cvt_pk_f32_fp8((int)q2, false);
            hi = __builtin_amdgcn_cvt_pk_f32_fp8((int)q2, true);
            acc.x = fmaf(lo.x, a2, acc.x); acc.y = fmaf(lo.y, a2, acc.y);
            acc.z = fmaf(hi.x, a2, acc.z); acc.w = fmaf(hi.y, a2, acc.w);
            lo = __builtin_amdgcn_cvt_pk_f32_fp8((int)q3, false);
            hi = __builtin_amdgcn_cvt_pk_f32_fp8((int)q3, true);
            acc.x = fmaf(lo.x, a3, acc.x); acc.y = fmaf(lo.y, a3, acc.y);
            acc.z = fmaf(hi.x, a3, acc.z); acc.w = fmaf(hi.y, a3, acc.w);
        }
        for (; i < m; ++i) {
            int s = __shfl(sv, i, 32);
            float a = exs[i * 4 + head];
            unsigned hq = h1q[(size_t)s * 32 + lane];
            f32x2 lo = __builtin_amdgcn_cvt_pk_f32_fp8((int)hq, false);
            f32x2 hi = __builtin_amdgcn_cvt_pk_f32_fp8((int)hq, true);
            acc.x = fmaf(lo.x, a, acc.x);
            acc.y = fmaf(lo.y, a, acc.y);
            acc.z = fmaf(hi.x, a, acc.z);
            acc.w = fmaf(hi.y, a, acc.w);
        }
        __builtin_amdgcn_wave_barrier();
    }
#pragma unroll
    for (int msk = 1; msk < 32; msk <<= 1) {
        dp.x += __shfl_xor(dp.x, msk, 32);
        dp.y += __shfl_xor(dp.y, msk, 32);
        dp.z += __shfl_xor(dp.z, msk, 32);
        dp.w += __shfl_xor(dp.w, msk, 32);
    }
    float inv = 1.f / f4get(dp, head);
    unsigned p0 = (unsigned)f2bf(acc.x * inv) | ((unsigned)f2bf(acc.y * inv) << 16);
    unsigned p1 = (unsigned)f2bf(acc.z * inv) | ((unsigned)f2bf(acc.w * inv) << 16);
    uint2 pk; pk.x = p0; pk.y = p1;
    *(uint2*)&out1b[(size_t)node * 64 + lane * 2] = pk;
}

// ---- GEMM2: proven round-4 inner loop; staging unpacks bf16 out1 ----
__global__ __launch_bounds__(256) void k_gemm2(const unsigned* __restrict__ in_b,
                                               const float* __restrict__ W2,
                                               const float* __restrict__ b1,
                                               const float* __restrict__ a2s,
                                               const float* __restrict__ a2d,
                                               unsigned short* __restrict__ h2b,
                                               float* __restrict__ as2,
                                               float* __restrict__ ad2) {
    __shared__ float sW[128 * 40];
    __shared__ float sX[128 * 132];
    int t = threadIdx.x;
    for (int i = t; i < 128 * 40 / 4; i += 256) ((float4*)sW)[i] = ((const float4*)W2)[i];
    int nbase = blockIdx.x * 128;
    int nrows = NNODES - nbase; if (nrows > 128) nrows = 128;
    {
        const uint4* X4 = (const uint4*)(in_b + (size_t)nbase * 64);
        for (int i = t; i < nrows * 16; i += 256) {
            int row = i >> 4, c8 = i & 15;
            uint4 v = X4[i];
            float4 bb0 = *(const float4*)&b1[c8 * 8];
            float4 bb1 = *(const float4*)&b1[c8 * 8 + 4];
            float f0 = bf_lo(v.x) + bb0.x, f1 = bf_hi(v.x) + bb0.y;
            float f2 = bf_lo(v.y) + bb0.z, f3 = bf_hi(v.y) + bb0.w;
            float f4 = bf_lo(v.z) + bb1.x, f5 = bf_hi(v.z) + bb1.y;
            float f6 = bf_lo(v.w) + bb1.z, f7 = bf_hi(v.w) + bb1.w;
            f0 = f0 > 0.f ? f0 : __expf(f0) - 1.f;
            f1 = f1 > 0.f ? f1 : __expf(f1) - 1.f;
            f2 = f2 > 0.f ? f2 : __expf(f2) - 1.f;
            f3 = f3 > 0.f ? f3 : __expf(f3) - 1.f;
            f4 = f4 > 0.f ? f4 : __expf(f4) - 1.f;
            f5 = f5 > 0.f ? f5 : __expf(f5) - 1.f;
            f6 = f6 > 0.f ? f6 : __expf(f6) - 1.f;
            f7 = f7 > 0.f ? f7 : __expf(f7) - 1.f;
            float* sp = &sX[row * 132 + c8 * 8];
            *(float4*)sp       = make_float4(f0, f1, f2, f3);
            *(float4*)(sp + 4) = make_float4(f4, f5, f6, f7);
        }
    }
    __syncthreads();

    int colg = t & 7, nodeg = t >> 3;
    int c0 = colg * 5;
    float acc[4][5];
#pragma unroll
    for (int i = 0; i < 4; ++i)
#pragma unroll
        for (int c = 0; c < 5; ++c) acc[i][c] = 0.f;

    for (int k = 0; k < 128; k += 4) {
        float4 xv[4];
#pragma unroll
        for (int i = 0; i < 4; ++i)
            xv[i] = *(const float4*)&sX[(nodeg + 32 * i) * 132 + k];
#pragma unroll
        for (int j = 0; j < 4; ++j) {
            float w0 = sW[(k + j) * 40 + c0 + 0];
            float w1 = sW[(k + j) * 40 + c0 + 1];
            float w2 = sW[(k + j) * 40 + c0 + 2];
            float w3 = sW[(k + j) * 40 + c0 + 3];
            float w4 = sW[(k + j) * 40 + c0 + 4];
#pragma unroll
            for (int i = 0; i < 4; ++i) {
                float xs = f4get(xv[i], j);
                acc[i][0] = fmaf(xs, w0, acc[i][0]);
                acc[i][1] = fmaf(xs, w1, acc[i][1]);
                acc[i][2] = fmaf(xs, w2, acc[i][2]);
                acc[i][3] = fmaf(xs, w3, acc[i][3]);
                acc[i][4] = fmaf(xs, w4, acc[i][4]);
            }
        }
    }

    float ws0 = a2s[c0], ws1 = a2s[c0 + 1], ws2 = a2s[c0 + 2], ws3 = a2s[c0 + 3], ws4 = a2s[c0 + 4];
    float wd0 = a2d[c0], wd1 = a2d[c0 + 1], wd2 = a2d[c0 + 2], wd3 = a2d[c0 + 3], wd4 = a2d[c0 + 4];
#pragma unroll
    for (int i = 0; i < 4; ++i) {
        int n = nodeg + 32 * i;
        float ps = acc[i][0]*ws0 + acc[i][1]*ws1 + acc[i][2]*ws2 + acc[i][3]*ws3 + acc[i][4]*ws4;
        float pd = acc[i][0]*wd0 + acc[i][1]*wd1 + acc[i][2]*wd2 + acc[i][3]*wd3 + acc[i][4]*wd4;
        ps += __shfl_xor(ps, 1); ps += __shfl_xor(ps, 2); ps += __shfl_xor(ps, 4);
        pd += __shfl_xor(pd, 1); pd += __shfl_xor(pd, 2); pd += __shfl_xor(pd, 4);
        if (n < nrows) {
            unsigned short* hp = h2b + (size_t)(nbase + n) * 40 + c0;
#pragma unroll
            for (int c = 0; c < 5; ++c) hp[c] = f2bf(acc[i][c]);
            if (colg == 0) {
                as2[nbase + n] = ps;
                ad2[nbase + n] = pd;
            }
        }
    }
}

// -------- layer-2 aggregation: 4x-unrolled gather --------
__global__ __launch_bounds__(256) void k_node2(const int* __restrict__ csr_src,
        const int* __restrict__ offs, const int* __restrict__ cnt,
        const unsigned short* __restrict__ h2b,
        const float* __restrict__ as2, const float* __restrict__ ad2,
        float* __restrict__ out2) {
    int t = threadIdx.x;
    int grp = t >> 4, lane = t & 15;
    int node = blockIdx.x * 16 + grp;
    if (node >= NNODES) return;
    int off = offs[node];
    int deg = cnt[(size_t)node * CSTR];
    float adv = ad2[node];
    float dp = 0.f;
    float4 acc = make_float4(0.f, 0.f, 0.f, 0.f);

    for (int base = 0; base < deg; base += 16) {
        int m = deg - base; if (m > 16) m = 16;
        int sv = 0; float ex = 0.f;
        if (lane < m) {
            sv = csr_src[off + base + lane];
            float v = as2[sv] + adv;
            v = v > 0.f ? v : NEG * v;
            ex = __expf(v);
            dp += ex;
        }
        int i = 0;
        for (; i + 4 <= m; i += 4) {
            int s0 = __shfl(sv, i + 0, 16);
            int s1 = __shfl(sv, i + 1, 16);
            int s2 = __shfl(sv, i + 2, 16);
            int s3 = __shfl(sv, i + 3, 16);
            float a0 = __shfl(ex, i + 0, 16);
            float a1 = __shfl(ex, i + 1, 16);
            float a2 = __shfl(ex, i + 2, 16);
            float a3 = __shfl(ex, i + 3, 16);
            if (lane < 10) {
                uint2 h0 = *(const uint2*)(h2b + (size_t)s0 * 40 + lane * 4);
                uint2 h1 = *(const uint2*)(h2b + (size_t)s1 * 40 + lane * 4);
                uint2 h2 = *(const uint2*)(h2b + (size_t)s2 * 40 + lane * 4);
                uint2 h3 = *(const uint2*)(h2b + (size_t)s3 * 40 + lane * 4);
                acc.x = fmaf(bf_lo(h0.x), a0, acc.x); acc.y = fmaf(bf_hi(h0.x), a0, acc.y);
                acc.z = fmaf(bf_lo(h0.y), a0, acc.z); acc.w = fmaf(bf_hi(h0.y), a0, acc.w);
                acc.x = fmaf(bf_lo(h1.x), a1, acc.x); acc.y = fmaf(bf_hi(h1.x), a1, acc.y);
                acc.z = fmaf(bf_lo(h1.y), a1, acc.z); acc.w = fmaf(bf_hi(h1.y), a1, acc.w);
                acc.x = fmaf(bf_lo(h2.x), a2, acc.x); acc.y = fmaf(bf_hi(h2.x), a2, acc.y);
                acc.z = fmaf(bf_lo(h2.y), a2, acc.z); acc.w = fmaf(bf_hi(h2.y), a2, acc.w);
                acc.x = fmaf(bf_lo(h3.x), a3, acc.x); acc.y = fmaf(bf_hi(h3.x), a3, acc.y);
                acc.z = fmaf(bf_lo(h3.y), a3, acc.z); acc.w = fmaf(bf_hi(h3.y), a3, acc.w);
            }
        }
        for (; i < m; ++i) {
            int s = __shfl(sv, i, 16);
            float a = __shfl(ex, i, 16);
            if (lane < 10) {
                uint2 hv = *(const uint2*)(h2b + (size_t)s * 40 + lane * 4);
                acc.x = fmaf(bf_lo(hv.x), a, acc.x);
                acc.y = fmaf(bf_hi(hv.x), a, acc.y);
                acc.z = fmaf(bf_lo(hv.y), a, acc.z);
                acc.w = fmaf(bf_hi(hv.y), a, acc.w);
            }
        }
    }
#pragma unroll
    for (int msk = 1; msk < 16; msk <<= 1) dp += __shfl_xor(dp, msk, 16);
    float inv = 1.f / dp;
    if (lane < 10) {
        float4 o; o.x = acc.x * inv; o.y = acc.y * inv; o.z = acc.z * inv; o.w = acc.w * inv;
        *(float4*)(out2 + (size_t)node * 40 + lane * 4) = o;
    }
}

// -------- parallel global mean pool --------
__global__ __launch_bounds__(256) void k_pool1(const float* __restrict__ out2,
        const int* __restrict__ batch, float* __restrict__ partial) {
    int t = threadIdx.x;
    if (t >= 240) return;
    int r = t / 40, c = t - r * 40;
    int base = blockIdx.x * PCH;
    int end = base + PCH; if (end > NNODES) end = NNODES;
    float sum = 0.f; int gcur = -1;
    for (int n = base + r; n < end; n += 6) {
        int g = batch[n];
        if (g != gcur) {
            if (gcur >= 0) unsafeAtomicAdd(&partial[gcur * 40 + c], sum);
            gcur = g; sum = 0.f;
        }
        sum += out2[(size_t)n * 40 + c];
    }
    if (gcur >= 0) unsafeAtomicAdd(&partial[gcur * 40 + c], sum);
}

__global__ void k_pool2(const float* __restrict__ partial, const int* __restrict__ batch,
                        const float* __restrict__ b2, float* __restrict__ out) {
    int i = blockIdx.x * 256 + threadIdx.x;
    if (i >= NGRAPH * 40) return;
    int g = i / 40, c = i - g * 40;
    int lo, hi;
    { int a = 0, b = NNODES; while (a < b) { int m = (a + b) >> 1; if (batch[m] < g) a = m + 1; else b = m; } lo = a; }
    { int a = lo, b = NNODES; while (a < b) { int m = (a + b) >> 1; if (batch[m] < g + 1) a = m + 1; else b = m; } hi = a; }
    int cntg = hi - lo;
    out[i] = cntg > 0 ? partial[i] / (float)cntg + b2[c] : 0.f;
}

extern "C" void kernel_launch(void* const* d_in, const int* in_sizes, int n_in,
                              void* d_out, int out_size, void* d_ws, size_t ws_size,
                              hipStream_t stream) {
    const float* x    = (const float*)d_in[0];
    const int*   ei   = (const int*)d_in[1];
    const int*   batch= (const int*)d_in[2];
    const float* W1   = (const float*)d_in[3];
    const float* a1s  = (const float*)d_in[4];
    const float* a1d  = (const float*)d_in[5];
    const float* b1   = (const float*)d_in[6];
    const float* W2   = (const float*)d_in[7];
    const float* a2s  = (const float*)d_in[8];
    const float* a2d  = (const float*)d_in[9];
    const float* b2   = (const float*)d_in[10];
    float* out = (float*)d_out;

    // ---- workspace layout ----
    int* cnt      = (int*)d_ws;                     // N*16 (padded; init by k_init)
    float* partial= (float*)(cnt + (size_t)NNODES * CSTR);   // 2560 (init by k_init)
    int* excl     = (int*)(partial + NGRAPH * 40);  // N
    int* offs     = excl + NNODES;                  // N
    int* bsum     = offs + NNODES;                  // 128
    int* rank     = bsum + 128;                     // NEDGES
    int* csr      = rank + NEDGES;                  // ETOT
    float* as1    = (float*)(csr + ETOT);           // N*4
    float* ad1    = as1 + (size_t)NNODES * 4;       // N*4
    unsigned* h1q = (unsigned*)(ad1 + (size_t)NNODES * 4);   // N*32 uint (fp8 x4)
    unsigned* out1b = h1q + (size_t)NNODES * 32;    // N*64 uint (bf16 x2)
    float* as2    = (float*)(out1b + (size_t)NNODES * 64);   // N
    float* ad2    = as2 + NNODES;                   // N
    unsigned short* h2b = (unsigned short*)(ad2 + NNODES);   // N*40 bf16
    float* out2   = (float*)(h2b + (size_t)NNODES * 40);     // N*40 f32

    // init: cnt=1 (self-loop pre-counted), partial=0
    k_init<<<NB_SCAN, 256, 0, stream>>>(cnt, partial);

    // fused hist + gemm1 (independent work, co-scheduled)
    k_fused1<<<2 * NHB, 256, 0, stream>>>(ei, cnt, rank, x, W1, a1s, a1d, h1q, as1, ad1);

    // CSR build (rest)
    k_scan1<<<NB_SCAN, 256, 0, stream>>>(cnt, excl, bsum);
    k_offs<<<NB_SCAN, 256, 0, stream>>>(excl, bsum, offs);
    k_scatter<<<NPART * SCAT_BPP, 256, 0, stream>>>(ei, rank, offs, csr);

    // layer 1 aggregation
    k_node1<<<(NNODES + 7) / 8, 256, 0, stream>>>(csr, offs, cnt, h1q,
                                                  (const float4*)as1, (const float4*)ad1, out1b);

    // layer 2
    k_gemm2<<<(NNODES + 127) / 128, 256, 0, stream>>>(out1b, W2, b1, a2s, a2d, h2b, as2, ad2);
    k_node2<<<(NNODES + 15) / 16, 256, 0, stream>>>(csr, offs, cnt, h2b, as2, ad2, out2);

    // pool
    k_pool1<<<(NNODES + PCH - 1) / PCH, 256, 0, stream>>>(out2, batch, partial);
    k_pool2<<<(NGRAPH * 40 + 255) / 256, 256, 0, stream>>>(partial, batch, b2, out);
}

// Round 19
// 331.899 us; speedup vs baseline: 1.0450x; 1.0450x over previous
//
#include <hip/hip_runtime.h>

#define NNODES 100000
#define NEDGES 1600000
#define ETOT   1700000   // NEDGES + NNODES self-loops (csr slots)
#define NGRAPH 64
#define NEG    0.2f
#define NB_SCAN 98       // ceil(NNODES / 1024)
#define NPART  8
#define DPP    12500     // dst-nodes per scatter partition
#define SCAT_BPP 128
#define SCAT_CHR 12500   // real edges per scatter chunk
#define DSL    98        // self-loop slots per chunk
#define PCH    1024      // pool1 nodes per block
#define NGB    1563      // gemm1 blocks
#define HB     521       // hist blocks (3:1 gemm:hist)
#define HEPB   3072      // edges per hist block (12/thread)
#define FGRID  2084      // 4*HB = NGB + HB

using f32x2 = __attribute__((ext_vector_type(2))) float;

__device__ __forceinline__ float f4get(const float4& v, int j) {
    return j == 0 ? v.x : j == 1 ? v.y : j == 2 ? v.z : v.w;
}

__device__ __forceinline__ unsigned short f2bf(float f) {   // RNE f32->bf16
    unsigned u = __float_as_uint(f);
    u = (u + 0x7fffu + ((u >> 16) & 1u)) >> 16;
    return (unsigned short)u;
}
__device__ __forceinline__ float bf_lo(unsigned u) { return __uint_as_float(u << 16); }
__device__ __forceinline__ float bf_hi(unsigned u) { return __uint_as_float(u & 0xffff0000u); }

// ---- init: cnt[d]=1 (self-loop pre-counted), partial=0 ----
__global__ __launch_bounds__(256) void k_init(int* __restrict__ cnt, float* __restrict__ partial) {
    int t = threadIdx.x, b = blockIdx.x;
#pragma unroll
    for (int j = 0; j < 4; ++j) {
        int idx = b * 1024 + t * 4 + j;
        if (idx < NNODES) cnt[idx] = 1;
    }
    int pi = b * 256 + t;
    if (pi < NGRAPH * 40) partial[pi] = 0.f;
}

// ===== FUSED: gemm1 (3 of 4 blocks) + hist (1 of 4, grid-striding real edges) =====
__global__ __launch_bounds__(256, 4) void k_fused1(const int* __restrict__ ei,
        int* __restrict__ cnt, int* __restrict__ rank,
        const float* __restrict__ x, const float* __restrict__ W1,
        const float* __restrict__ a1s, const float* __restrict__ a1d,
        unsigned* __restrict__ h1q, float* __restrict__ as1, float* __restrict__ ad1) {
    __shared__ float sX[64 * 128];    // 32 KB (gemm role only)
    int bid = blockIdx.x;
    if ((bid & 3) == 3) {
        // ---- hist role: 12 real edges/thread, 4-batched; ranks start at 1 ----
        int hb = bid >> 2;
        int t = threadIdx.x;
        int e0 = hb * HEPB;
        int e1 = e0 + HEPB; if (e1 > NEDGES) e1 = NEDGES;
        for (int e = e0 + t; e < e1; e += 1024) {
            int eA = e, eB = e + 256, eC = e + 512, eD = e + 768;
            bool vA = eA < e1, vB = eB < e1, vC = eC < e1, vD = eD < e1;
            int dA = 0, dB = 0, dC = 0, dD = 0;
            if (vA) dA = ei[NEDGES + eA];
            if (vB) dB = ei[NEDGES + eB];
            if (vC) dC = ei[NEDGES + eC];
            if (vD) dD = ei[NEDGES + eD];
            int rA = 0, rB = 0, rC = 0, rD = 0;
            if (vA) rA = atomicAdd(&cnt[dA], 1);
            if (vB) rB = atomicAdd(&cnt[dB], 1);
            if (vC) rC = atomicAdd(&cnt[dC], 1);
            if (vD) rD = atomicAdd(&cnt[dD], 1);
            if (vA) rank[eA] = rA;
            if (vB) rank[eB] = rB;
            if (vC) rank[eC] = rC;
            if (vD) rank[eD] = rD;
        }
        return;
    }
    // ---- gemm1 role ----
    int gb = (bid >> 2) * 3 + (bid & 3);
    if (gb >= NGB) return;
    int t = threadIdx.x;
    int nbase = gb * 64;
    int nrows = NNODES - nbase; if (nrows > 64) nrows = 64;
    {
        const float4* X4 = (const float4*)(x + (size_t)nbase * 128);
        float4* sX4 = (float4*)sX;
        for (int i = t; i < nrows * 32; i += 256) sX4[i] = X4[i];
    }
    __syncthreads();

    int colg = t & 31, rowg = t >> 5;
    int c0 = colg * 4, n0 = rowg * 8;
    float acc[8][4];
#pragma unroll
    for (int i = 0; i < 8; ++i)
        acc[i][0] = acc[i][1] = acc[i][2] = acc[i][3] = 0.f;

    for (int k = 0; k < 128; k += 4) {
        float4 w0 = *(const float4*)&W1[(size_t)(k + 0) * 128 + c0];
        float4 w1 = *(const float4*)&W1[(size_t)(k + 1) * 128 + c0];
        float4 w2 = *(const float4*)&W1[(size_t)(k + 2) * 128 + c0];
        float4 w3 = *(const float4*)&W1[(size_t)(k + 3) * 128 + c0];
#pragma unroll
        for (int i = 0; i < 8; ++i) {
            float4 xv = *(const float4*)&sX[(n0 + i) * 128 + k];
            acc[i][0] = fmaf(xv.x, w0.x, acc[i][0]); acc[i][1] = fmaf(xv.x, w0.y, acc[i][1]);
            acc[i][2] = fmaf(xv.x, w0.z, acc[i][2]); acc[i][3] = fmaf(xv.x, w0.w, acc[i][3]);
            acc[i][0] = fmaf(xv.y, w1.x, acc[i][0]); acc[i][1] = fmaf(xv.y, w1.y, acc[i][1]);
            acc[i][2] = fmaf(xv.y, w1.z, acc[i][2]); acc[i][3] = fmaf(xv.y, w1.w, acc[i][3]);
            acc[i][0] = fmaf(xv.z, w2.x, acc[i][0]); acc[i][1] = fmaf(xv.z, w2.y, acc[i][1]);
            acc[i][2] = fmaf(xv.z, w2.z, acc[i][2]); acc[i][3] = fmaf(xv.z, w2.w, acc[i][3]);
            acc[i][0] = fmaf(xv.w, w3.x, acc[i][0]); acc[i][1] = fmaf(xv.w, w3.y, acc[i][1]);
            acc[i][2] = fmaf(xv.w, w3.z, acc[i][2]); acc[i][3] = fmaf(xv.w, w3.w, acc[i][3]);
        }
    }

    int head = colg >> 3;
    float ws0 = a1s[c0], ws1 = a1s[c0 + 1], ws2 = a1s[c0 + 2], ws3 = a1s[c0 + 3];
    float wd0 = a1d[c0], wd1 = a1d[c0 + 1], wd2 = a1d[c0 + 2], wd3 = a1d[c0 + 3];
#pragma unroll
    for (int i = 0; i < 8; ++i) {
        int n = n0 + i;
        float ps = acc[i][0] * ws0 + acc[i][1] * ws1 + acc[i][2] * ws2 + acc[i][3] * ws3;
        float pd = acc[i][0] * wd0 + acc[i][1] * wd1 + acc[i][2] * wd2 + acc[i][3] * wd3;
        ps += __shfl_xor(ps, 1); ps += __shfl_xor(ps, 2); ps += __shfl_xor(ps, 4);
        pd += __shfl_xor(pd, 1); pd += __shfl_xor(pd, 2); pd += __shfl_xor(pd, 4);
        if (n < nrows) {
            int q = __builtin_amdgcn_cvt_pk_fp8_f32(acc[i][0], acc[i][1], 0, false);
            q = __builtin_amdgcn_cvt_pk_fp8_f32(acc[i][2], acc[i][3], q, true);
            h1q[((size_t)(nbase + n)) * 32 + colg] = (unsigned)q;
            if ((colg & 7) == 0) {
                as1[(size_t)(nbase + n) * 4 + head] = ps;
                ad1[(size_t)(nbase + n) * 4 + head] = pd;
            }
        }
    }
}

__global__ __launch_bounds__(256) void k_scan1(const int* __restrict__ cnt,
                                               int* __restrict__ excl,
                                               int* __restrict__ bsum) {
    __shared__ int tmp[256];
    int t = threadIdx.x;
    int base = blockIdx.x * 1024 + t * 4;
    int v0 = base + 0 < NNODES ? cnt[base + 0] : 0;
    int v1 = base + 1 < NNODES ? cnt[base + 1] : 0;
    int v2 = base + 2 < NNODES ? cnt[base + 2] : 0;
    int v3 = base + 3 < NNODES ? cnt[base + 3] : 0;
    int tot = v0 + v1 + v2 + v3;
    tmp[t] = tot;
    __syncthreads();
    for (int off = 1; off < 256; off <<= 1) {
        int x = (t >= off) ? tmp[t - off] : 0;
        __syncthreads();
        tmp[t] += x;
        __syncthreads();
    }
    int tbase = tmp[t] - tot;
    if (base + 0 < NNODES) excl[base + 0] = tbase;
    if (base + 1 < NNODES) excl[base + 1] = tbase + v0;
    if (base + 2 < NNODES) excl[base + 2] = tbase + v0 + v1;
    if (base + 3 < NNODES) excl[base + 3] = tbase + v0 + v1 + v2;
    if (t == 255) bsum[blockIdx.x] = tmp[255];
}

// offs[n] = global exclusive prefix
__global__ __launch_bounds__(256) void k_offs(const int* __restrict__ excl,
                                              const int* __restrict__ bsum,
                                              int* __restrict__ offs) {
    __shared__ int sp;
    int b = blockIdx.x, t = threadIdx.x;
    if (t == 0) {
        int p = 0;
        for (int i = 0; i < b; ++i) p += bsum[i];
        sp = p;
    }
    __syncthreads();
    int prefix = sp;
#pragma unroll
    for (int j = 0; j < 4; ++j) {
        int idx = b * 1024 + t * 4 + j;
        if (idx < NNODES) offs[idx] = excl[idx] + prefix;
    }
}

// dst-range partitioned scatter: real edges (ranks >=1) + self-loop slot-0 writes
__global__ __launch_bounds__(256) void k_scatter(const int* __restrict__ ei,
                                                 const int* __restrict__ rank,
                                                 const int* __restrict__ offs,
                                                 int* __restrict__ csr_src) {
    int p = blockIdx.x & (NPART - 1);
    int chunk = blockIdx.x / NPART;
    int dlo = p * DPP, dhi = dlo + DPP;
    {
        int d = dlo + chunk * DSL + threadIdx.x;
        if (threadIdx.x < DSL && d < dhi) csr_src[offs[d]] = d;
    }
    int e0 = chunk * SCAT_CHR;
    int e1 = e0 + SCAT_CHR; if (e1 > NEDGES) e1 = NEDGES;
    for (int e = e0 + threadIdx.x; e < e1; e += 1024) {
        int eA = e, eB = e + 256, eC = e + 512, eD = e + 768;
        bool vA = eA < e1, vB = eB < e1, vC = eC < e1, vD = eD < e1;
        int dA = -1, dB = -1, dC = -1, dD = -1;
        if (vA) dA = ei[NEDGES + eA];
        if (vB) dB = ei[NEDGES + eB];
        if (vC) dC = ei[NEDGES + eC];
        if (vD) dD = ei[NEDGES + eD];
        if (dA >= dlo && dA < dhi) csr_src[offs[dA] + rank[eA]] = ei[eA];
        if (dB >= dlo && dB < dhi) csr_src[offs[dB] + rank[eB]] = ei[eB];
        if (dC >= dlo && dC < dhi) csr_src[offs[dC] + rank[eC]] = ei[eC];
        if (dD >= dlo && dD < dhi) csr_src[offs[dD] + rank[eD]] = ei[eD];
    }
}

// -------- layer-1 aggregation: 32-lane groups, 4x-unrolled gather --------
__global__ __launch_bounds__(256) void k_node1(const int* __restrict__ csr_src,
        const int* __restrict__ offs, const int* __restrict__ cnt,
        const unsigned* __restrict__ h1q,
        const float4* __restrict__ as1v, const float4* __restrict__ ad1v,
        unsigned* __restrict__ out1b) {
    __shared__ float4 exbuf[8][32];
    int t = threadIdx.x;
    int grp = t >> 5, lane = t & 31;
    int node = blockIdx.x * 8 + grp;
    if (node >= NNODES) return;
    int head = lane >> 3;
    int off = offs[node];
    int deg = cnt[node];
    float4 adv = ad1v[node];
    float4 dp = make_float4(0.f, 0.f, 0.f, 0.f);
    float4 acc = make_float4(0.f, 0.f, 0.f, 0.f);
    const float* exs = (const float*)&exbuf[grp][0];

    for (int base = 0; base < deg; base += 32) {
        int m = deg - base; if (m > 32) m = 32;
        int sv = 0;
        if (lane < m) {
            sv = csr_src[off + base + lane];
            float4 av = as1v[sv];
            float v; float4 e;
            v = av.x + adv.x; v = v > 0.f ? v : NEG * v; e.x = __expf(v);
            v = av.y + adv.y; v = v > 0.f ? v : NEG * v; e.y = __expf(v);
            v = av.z + adv.z; v = v > 0.f ? v : NEG * v; e.z = __expf(v);
            v = av.w + adv.w; v = v > 0.f ? v : NEG * v; e.w = __expf(v);
            exbuf[grp][lane] = e;
            dp.x += e.x; dp.y += e.y; dp.z += e.z; dp.w += e.w;
        }
        __builtin_amdgcn_wave_barrier();
        int i = 0;
        for (; i + 4 <= m; i += 4) {
            int s0 = __shfl(sv, i + 0, 32);
            int s1 = __shfl(sv, i + 1, 32);
            int s2 = __shfl(sv, i + 2, 32);
            int s3 = __shfl(sv, i + 3, 32);
            unsigned q0 = h1q[(size_t)s0 * 32 + lane];
            unsigned q1 = h1q[(size_t)s1 * 32 + lane];
            unsigned q2 = h1q[(size_t)s2 * 32 + lane];
            unsigned q3 = h1q[(size_t)s3 * 32 + lane];
            float a0 = exs[(i + 0) * 4 + head];
            float a1 = exs[(i + 1) * 4 + head];
            float a2 = exs[(i + 2) * 4 + head];
            float a3 = exs[(i + 3) * 4 + head];
            f32x2 lo, hi;
            lo = __builtin_amdgcn_cvt_pk_f32_fp8((int)q0, false);
            hi = __builtin_amdgcn_cvt_pk_f32_fp8((int)q0, true);
            acc.x = fmaf(lo.x, a0, acc.x); acc.y = fmaf(lo.y, a0, acc.y);
            acc.z = fmaf(hi.x, a0, acc.z); acc.w = fmaf(hi.y, a0, acc.w);
            lo = __builtin_amdgcn_cvt_pk_f32_fp8((int)q1, false);
            hi = __builtin_amdgcn_cvt_pk_f32_fp8((int)q1, true);
            acc.x = fmaf(lo.x, a1, acc.x); acc.y = fmaf(lo.y, a1, acc.y);
            acc.z = fmaf(hi.x, a1, acc.z); acc.w = fmaf(hi.y, a1, acc.w);
            lo = __builtin_amdgcn_cvt_pk_f32_fp8((int)q2, false);
            hi = __builtin_amdgcn_cvt_pk_f32_fp8((int)q2, true);
            acc.x = fmaf(lo.x, a2, acc.x); acc.y = fmaf(lo.y, a2, acc.y);
            acc.z = fmaf(hi.x, a2, acc.z); acc.w = fmaf(hi.y, a2, acc.w);
            lo = __builtin_amdgcn_cvt_pk_f32_fp8((int)q3, false);
            hi = __builtin_amdgcn_cvt_pk_f32_fp8((int)q3, true);
            acc.x = fmaf(lo.x, a3, acc.x); acc.y = fmaf(lo.y, a3, acc.y);
            acc.z = fmaf(hi.x, a3, acc.z); acc.w = fmaf(hi.y, a3, acc.w);
        }
        for (; i < m; ++i) {
            int s = __shfl(sv, i, 32);
            float a = exs[i * 4 + head];
            unsigned hq = h1q[(size_t)s * 32 + lane];
            f32x2 lo = __builtin_amdgcn_cvt_pk_f32_fp8((int)hq, false);
            f32x2 hi = __builtin_amdgcn_cvt_pk_f32_fp8((int)hq, true);
            acc.x = fmaf(lo.x, a, acc.x);
            acc.y = fmaf(lo.y, a, acc.y);
            acc.z = fmaf(hi.x, a, acc.z);
            acc.w = fmaf(hi.y, a, acc.w);
        }
        __builtin_amdgcn_wave_barrier();
    }
#pragma unroll
    for (int msk = 1; msk < 32; msk <<= 1) {
        dp.x += __shfl_xor(dp.x, msk, 32);
        dp.y += __shfl_xor(dp.y, msk, 32);
        dp.z += __shfl_xor(dp.z, msk, 32);
        dp.w += __shfl_xor(dp.w, msk, 32);
    }
    float inv = 1.f / f4get(dp, head);
    unsigned p0 = (unsigned)f2bf(acc.x * inv) | ((unsigned)f2bf(acc.y * inv) << 16);
    unsigned p1 = (unsigned)f2bf(acc.z * inv) | ((unsigned)f2bf(acc.w * inv) << 16);
    uint2 pk; pk.x = p0; pk.y = p1;
    *(uint2*)&out1b[(size_t)node * 64 + lane * 2] = pk;
}

// ---- GEMM2: proven round-4 inner loop; staging unpacks bf16 out1 ----
__global__ __launch_bounds__(256) void k_gemm2(const unsigned* __restrict__ in_b,
                                               const float* __restrict__ W2,
                                               const float* __restrict__ b1,
                                               const float* __restrict__ a2s,
                                               const float* __restrict__ a2d,
                                               unsigned short* __restrict__ h2b,
                                               float* __restrict__ as2,
                                               float* __restrict__ ad2) {
    __shared__ float sW[128 * 40];
    __shared__ float sX[128 * 132];
    int t = threadIdx.x;
    for (int i = t; i < 128 * 40 / 4; i += 256) ((float4*)sW)[i] = ((const float4*)W2)[i];
    int nbase = blockIdx.x * 128;
    int nrows = NNODES - nbase; if (nrows > 128) nrows = 128;
    {
        const uint4* X4 = (const uint4*)(in_b + (size_t)nbase * 64);
        for (int i = t; i < nrows * 16; i += 256) {
            int row = i >> 4, c8 = i & 15;
            uint4 v = X4[i];
            float4 bb0 = *(const float4*)&b1[c8 * 8];
            float4 bb1 = *(const float4*)&b1[c8 * 8 + 4];
            float f0 = bf_lo(v.x) + bb0.x, f1 = bf_hi(v.x) + bb0.y;
            float f2 = bf_lo(v.y) + bb0.z, f3 = bf_hi(v.y) + bb0.w;
            float f4 = bf_lo(v.z) + bb1.x, f5 = bf_hi(v.z) + bb1.y;
            float f6 = bf_lo(v.w) + bb1.z, f7 = bf_hi(v.w) + bb1.w;
            f0 = f0 > 0.f ? f0 : __expf(f0) - 1.f;
            f1 = f1 > 0.f ? f1 : __expf(f1) - 1.f;
            f2 = f2 > 0.f ? f2 : __expf(f2) - 1.f;
            f3 = f3 > 0.f ? f3 : __expf(f3) - 1.f;
            f4 = f4 > 0.f ? f4 : __expf(f4) - 1.f;
            f5 = f5 > 0.f ? f5 : __expf(f5) - 1.f;
            f6 = f6 > 0.f ? f6 : __expf(f6) - 1.f;
            f7 = f7 > 0.f ? f7 : __expf(f7) - 1.f;
            float* sp = &sX[row * 132 + c8 * 8];
            *(float4*)sp       = make_float4(f0, f1, f2, f3);
            *(float4*)(sp + 4) = make_float4(f4, f5, f6, f7);
        }
    }
    __syncthreads();

    int colg = t & 7, nodeg = t >> 3;
    int c0 = colg * 5;
    float acc[4][5];
#pragma unroll
    for (int i = 0; i < 4; ++i)
#pragma unroll
        for (int c = 0; c < 5; ++c) acc[i][c] = 0.f;

    for (int k = 0; k < 128; k += 4) {
        float4 xv[4];
#pragma unroll
        for (int i = 0; i < 4; ++i)
            xv[i] = *(const float4*)&sX[(nodeg + 32 * i) * 132 + k];
#pragma unroll
        for (int j = 0; j < 4; ++j) {
            float w0 = sW[(k + j) * 40 + c0 + 0];
            float w1 = sW[(k + j) * 40 + c0 + 1];
            float w2 = sW[(k + j) * 40 + c0 + 2];
            float w3 = sW[(k + j) * 40 + c0 + 3];
            float w4 = sW[(k + j) * 40 + c0 + 4];
#pragma unroll
            for (int i = 0; i < 4; ++i) {
                float xs = f4get(xv[i], j);
                acc[i][0] = fmaf(xs, w0, acc[i][0]);
                acc[i][1] = fmaf(xs, w1, acc[i][1]);
                acc[i][2] = fmaf(xs, w2, acc[i][2]);
                acc[i][3] = fmaf(xs, w3, acc[i][3]);
                acc[i][4] = fmaf(xs, w4, acc[i][4]);
            }
        }
    }

    float ws0 = a2s[c0], ws1 = a2s[c0 + 1], ws2 = a2s[c0 + 2], ws3 = a2s[c0 + 3], ws4 = a2s[c0 + 4];
    float wd0 = a2d[c0], wd1 = a2d[c0 + 1], wd2 = a2d[c0 + 2], wd3 = a2d[c0 + 3], wd4 = a2d[c0 + 4];
#pragma unroll
    for (int i = 0; i < 4; ++i) {
        int n = nodeg + 32 * i;
        float ps = acc[i][0]*ws0 + acc[i][1]*ws1 + acc[i][2]*ws2 + acc[i][3]*ws3 + acc[i][4]*ws4;
        float pd = acc[i][0]*wd0 + acc[i][1]*wd1 + acc[i][2]*wd2 + acc[i][3]*wd3 + acc[i][4]*wd4;
        ps += __shfl_xor(ps, 1); ps += __shfl_xor(ps, 2); ps += __shfl_xor(ps, 4);
        pd += __shfl_xor(pd, 1); pd += __shfl_xor(pd, 2); pd += __shfl_xor(pd, 4);
        if (n < nrows) {
            unsigned short* hp = h2b + (size_t)(nbase + n) * 40 + c0;
#pragma unroll
            for (int c = 0; c < 5; ++c) hp[c] = f2bf(acc[i][c]);
            if (colg == 0) {
                as2[nbase + n] = ps;
                ad2[nbase + n] = pd;
            }
        }
    }
}

// -------- layer-2 aggregation: 4x-unrolled gather --------
__global__ __launch_bounds__(256) void k_node2(const int* __restrict__ csr_src,
        const int* __restrict__ offs, const int* __restrict__ cnt,
        const unsigned short* __restrict__ h2b,
        const float* __restrict__ as2, const float* __restrict__ ad2,
        float* __restrict__ out2) {
    int t = threadIdx.x;
    int grp = t >> 4, lane = t & 15;
    int node = blockIdx.x * 16 + grp;
    if (node >= NNODES) return;
    int off = offs[node];
    int deg = cnt[node];
    float adv = ad2[node];
    float dp = 0.f;
    float4 acc = make_float4(0.f, 0.f, 0.f, 0.f);

    for (int base = 0; base < deg; base += 16) {
        int m = deg - base; if (m > 16) m = 16;
        int sv = 0; float ex = 0.f;
        if (lane < m) {
            sv = csr_src[off + base + lane];
            float v = as2[sv] + adv;
            v = v > 0.f ? v : NEG * v;
            ex = __expf(v);
            dp += ex;
        }
        int i = 0;
        for (; i + 4 <= m; i += 4) {
            int s0 = __shfl(sv, i + 0, 16);
            int s1 = __shfl(sv, i + 1, 16);
            int s2 = __shfl(sv, i + 2, 16);
            int s3 = __shfl(sv, i + 3, 16);
            float a0 = __shfl(ex, i + 0, 16);
            float a1 = __shfl(ex, i + 1, 16);
            float a2 = __shfl(ex, i + 2, 16);
            float a3 = __shfl(ex, i + 3, 16);
            if (lane < 10) {
                uint2 h0 = *(const uint2*)(h2b + (size_t)s0 * 40 + lane * 4);
                uint2 h1 = *(const uint2*)(h2b + (size_t)s1 * 40 + lane * 4);
                uint2 h2 = *(const uint2*)(h2b + (size_t)s2 * 40 + lane * 4);
                uint2 h3 = *(const uint2*)(h2b + (size_t)s3 * 40 + lane * 4);
                acc.x = fmaf(bf_lo(h0.x), a0, acc.x); acc.y = fmaf(bf_hi(h0.x), a0, acc.y);
                acc.z = fmaf(bf_lo(h0.y), a0, acc.z); acc.w = fmaf(bf_hi(h0.y), a0, acc.w);
                acc.x = fmaf(bf_lo(h1.x), a1, acc.x); acc.y = fmaf(bf_hi(h1.x), a1, acc.y);
                acc.z = fmaf(bf_lo(h1.y), a1, acc.z); acc.w = fmaf(bf_hi(h1.y), a1, acc.w);
                acc.x = fmaf(bf_lo(h2.x), a2, acc.x); acc.y = fmaf(bf_hi(h2.x), a2, acc.y);
                acc.z = fmaf(bf_lo(h2.y), a2, acc.z); acc.w = fmaf(bf_hi(h2.y), a2, acc.w);
                acc.x = fmaf(bf_lo(h3.x), a3, acc.x); acc.y = fmaf(bf_hi(h3.x), a3, acc.y);
                acc.z = fmaf(bf_lo(h3.y), a3, acc.z); acc.w = fmaf(bf_hi(h3.y), a3, acc.w);
            }
        }
        for (; i < m; ++i) {
            int s = __shfl(sv, i, 16);
            float a = __shfl(ex, i, 16);
            if (lane < 10) {
                uint2 hv = *(const uint2*)(h2b + (size_t)s * 40 + lane * 4);
                acc.x = fmaf(bf_lo(hv.x), a, acc.x);
                acc.y = fmaf(bf_hi(hv.x), a, acc.y);
                acc.z = fmaf(bf_lo(hv.y), a, acc.z);
                acc.w = fmaf(bf_hi(hv.y), a, acc.w);
            }
        }
    }
#pragma unroll
    for (int msk = 1; msk < 16; msk <<= 1) dp += __shfl_xor(dp, msk, 16);
    float inv = 1.f / dp;
    if (lane < 10) {
        float4 o; o.x = acc.x * inv; o.y = acc.y * inv; o.z = acc.z * inv; o.w = acc.w * inv;
        *(float4*)(out2 + (size_t)node * 40 + lane * 4) = o;
    }
}

// -------- parallel global mean pool --------
__global__ __launch_bounds__(256) void k_pool1(const float* __restrict__ out2,
        const int* __restrict__ batch, float* __restrict__ partial) {
    int t = threadIdx.x;
    if (t >= 240) return;
    int r = t / 40, c = t - r * 40;
    int base = blockIdx.x * PCH;
    int end = base + PCH; if (end > NNODES) end = NNODES;
    float sum = 0.f; int gcur = -1;
    for (int n = base + r; n < end; n += 6) {
        int g = batch[n];
        if (g != gcur) {
            if (gcur >= 0) unsafeAtomicAdd(&partial[gcur * 40 + c], sum);
            gcur = g; sum = 0.f;
        }
        sum += out2[(size_t)n * 40 + c];
    }
    if (gcur >= 0) unsafeAtomicAdd(&partial[gcur * 40 + c], sum);
}

__global__ void k_pool2(const float* __restrict__ partial, const int* __restrict__ batch,
                        const float* __restrict__ b2, float* __restrict__ out) {
    int i = blockIdx.x * 256 + threadIdx.x;
    if (i >= NGRAPH * 40) return;
    int g = i / 40, c = i - g * 40;
    int lo, hi;
    { int a = 0, b = NNODES; while (a < b) { int m = (a + b) >> 1; if (batch[m] < g) a = m + 1; else b = m; } lo = a; }
    { int a = lo, b = NNODES; while (a < b) { int m = (a + b) >> 1; if (batch[m] < g + 1) a = m + 1; else b = m; } hi = a; }
    int cntg = hi - lo;
    out[i] = cntg > 0 ? partial[i] / (float)cntg + b2[c] : 0.f;
}

extern "C" void kernel_launch(void* const* d_in, const int* in_sizes, int n_in,
                              void* d_out, int out_size, void* d_ws, size_t ws_size,
                              hipStream_t stream) {
    const float* x    = (const float*)d_in[0];
    const int*   ei   = (const int*)d_in[1];
    const int*   batch= (const int*)d_in[2];
    const float* W1   = (const float*)d_in[3];
    const float* a1s  = (const float*)d_in[4];
    const float* a1d  = (const float*)d_in[5];
    const float* b1   = (const float*)d_in[6];
    const float* W2   = (const float*)d_in[7];
    const float* a2s  = (const float*)d_in[8];
    const float* a2d  = (const float*)d_in[9];
    const float* b2   = (const float*)d_in[10];
    float* out = (float*)d_out;

    // ---- workspace layout ----
    int* cnt      = (int*)d_ws;                     // N (init=1 by k_init)
    float* partial= (float*)(cnt + NNODES);         // 2560 (init=0 by k_init)
    int* excl     = (int*)(partial + NGRAPH * 40);  // N
    int* offs     = excl + NNODES;                  // N
    int* bsum     = offs + NNODES;                  // 128
    int* rank     = bsum + 128;                     // NEDGES
    int* csr      = rank + NEDGES;                  // ETOT
    float* as1    = (float*)(csr + ETOT);           // N*4
    float* ad1    = as1 + (size_t)NNODES * 4;       // N*4
    unsigned* h1q = (unsigned*)(ad1 + (size_t)NNODES * 4);   // N*32 uint (fp8 x4)
    unsigned* out1b = h1q + (size_t)NNODES * 32;    // N*64 uint (bf16 x2)
    float* as2    = (float*)(out1b + (size_t)NNODES * 64);   // N
    float* ad2    = as2 + NNODES;                   // N
    unsigned short* h2b = (unsigned short*)(ad2 + NNODES);   // N*40 bf16
    float* out2   = (float*)(h2b + (size_t)NNODES * 40);     // N*40 f32

    // init: cnt=1 (self-loop pre-counted), partial=0
    k_init<<<NB_SCAN, 256, 0, stream>>>(cnt, partial);

    // fused gemm1 (3/4 blocks) + hist (1/4 blocks)
    k_fused1<<<FGRID, 256, 0, stream>>>(ei, cnt, rank, x, W1, a1s, a1d, h1q, as1, ad1);

    // CSR build (rest)
    k_scan1<<<NB_SCAN, 256, 0, stream>>>(cnt, excl, bsum);
    k_offs<<<NB_SCAN, 256, 0, stream>>>(excl, bsum, offs);
    k_scatter<<<NPART * SCAT_BPP, 256, 0, stream>>>(ei, rank, offs, csr);

    // layer 1 aggregation
    k_node1<<<(NNODES + 7) / 8, 256, 0, stream>>>(csr, offs, cnt, h1q,
                                                  (const float4*)as1, (const float4*)ad1, out1b);

    // layer 2
    k_gemm2<<<(NNODES + 127) / 128, 256, 0, stream>>>(out1b, W2, b1, a2s, a2d, h2b, as2, ad2);
    k_node2<<<(NNODES + 15) / 16, 256, 0, stream>>>(csr, offs, cnt, h2b, as2, ad2, out2);

    // pool
    k_pool1<<<(NNODES + PCH - 1) / PCH, 256, 0, stream>>>(out2, batch, partial);
    k_pool2<<<(NGRAPH * 40 + 255) / 256, 256, 0, stream>>>(partial, batch, b2, out);
}